// Round 7
// baseline (9066.071 us; speedup 1.0000x reference)
//
#include <hip/hip_runtime.h>

constexpr int BB = 64, TT = 512, DD = 512, HH = 512;
constexpr int GG = 4 * HH;          // 2048 gate cols
constexpr int KK = DD + HH;         // 1024 fused K
constexpr int NBLK = 256, NTHR = 512;
// LDS: A[32][2048B] swizzled (64KB) | zl[4][2][16][17] f32 (8.5KB) | mask (4KB)
constexpr int LDS_A  = 32 * 2048;
constexpr int LDS_ZL = 4 * 2 * 16 * 17 * 4;
constexpr int LDS_BYTES = LDS_A + LDS_ZL + 64 * 16 * 4;

using short8 = __attribute__((ext_vector_type(8))) short;
using f32x4  = __attribute__((ext_vector_type(4))) float;

__device__ __host__ __forceinline__ unsigned short f2bf(float f) {
    union { float f; unsigned u; } v; v.f = f;
    unsigned u = v.u + 0x7fffu + ((v.u >> 16) & 1u);   // RNE
    return (unsigned short)(u >> 16);
}

__device__ __forceinline__ float fsig(float x) {       // inf-safe fast sigmoid
    return 1.f / (1.f + __expf(-x));
}
__device__ __forceinline__ float ftanh_(float x) {     // inf-safe fast tanh
    float e = __expf(2.f * fabsf(x));
    float r = 1.f - 2.f / (e + 1.f);
    return copysignf(r, x);
}

// ws: WB[2048][1024] bf16 (4MB) | hbuf[2][BB*HH/2] u32 pairs (128KB)
//     | flags[256] (1KB) | mpack[64][16] (4KB)

__global__ void prep_kernel(const float* __restrict__ Wx,   // [DD][GG]
                            const float* __restrict__ Wr,   // [HH][GG]
                            const float* __restrict__ init_h,
                            const int*   __restrict__ mask, // [B,T]
                            unsigned short* __restrict__ WB,
                            unsigned* __restrict__ hbuf0,
                            unsigned* __restrict__ flags,
                            unsigned* __restrict__ mpack) {
    int idx = blockIdx.x * blockDim.x + threadIdx.x;
    if (idx < GG * KK) {                 // WB[g][k] = W[k][g], bf16
        int g = idx >> 10, k = idx & 1023;
        float v = (k < DD) ? Wx[(size_t)k * GG + g]
                           : Wr[(size_t)(k - DD) * GG + g];
        WB[idx] = f2bf(v);
    }
    if (idx < BB * HH / 2) {             // h0 as packed bf16 pairs
        unsigned lo = f2bf(init_h[2 * idx]);
        unsigned hi = f2bf(init_h[2 * idx + 1]);
        hbuf0[idx] = lo | (hi << 16);
    }
    if (idx < NBLK) flags[idx] = 0u;
    if (idx < 64 * 16) {
        int b = idx >> 4, w = idx & 15;
        unsigned word = 0u;
        for (int tb = 0; tb < 32; ++tb)
            word |= (mask[b * TT + w * 32 + tb] != 0 ? 1u : 0u) << tb;
        mpack[idx] = word;
    }
}

__global__ void __launch_bounds__(NTHR, 1)
lstm_kernel(const float* __restrict__ x,          // [B,T,D]
            const unsigned short* __restrict__ WB,// [2048][1024] bf16
            const float* __restrict__ bias,       // [GG]
            unsigned*    hbuf,                    // [2][B*H/2] u32
            unsigned*    flags,                   // [256]: [bh*128 + qid]
            const unsigned* __restrict__ mpack,   // [64][16]
            const float* __restrict__ init_h,
            const float* __restrict__ init_c,
            float* __restrict__ out)              // outputs | h_f | c_f
{
    extern __shared__ char smem[];                // A: [32 rows][2048B] swizzled
    float*    zlp   = (float*)(smem + LDS_A);     // [4][2][16][17]
    unsigned* m_lds = (unsigned*)(smem + LDS_A + LDS_ZL);

    const int tid = threadIdx.x;
    const int bid = blockIdx.x;
    const int w   = tid >> 6;          // wave 0..7
    const int l   = tid & 63;
    const int bt  = w & 1;             // b-tile (16 rows)
    const int ws  = w >> 1;            // k-quarter 0..3
    const int bh     = (bid >> 3) & 1;                 // batch half
    const int qid    = (bid & 7) * 16 + (bid >> 4);    // j-quad 0..127
    const int j_base = qid * 4;

    // ---- persistent B-fragments (validated R6 layout) ----
    const int n = l & 15;
    const int g = (n >> 2) * 512 + j_base + (n & 3);
    short8 bf[8];
    {
        const unsigned short* wrow = WB + (size_t)g * KK + (l >> 4) * 8;
        #pragma unroll
        for (int i = 0; i < 8; ++i) {
            int kt = (i < 4) ? (ws * 4 + i) : (16 + ws * 4 + (i - 4));
            bf[i] = *(const short8*)(wrow + kt * 32);
        }
    }

    // ---- update mapping (tid < 128): one (b row, j col) each ----
    const int ub = tid >> 2, jp = tid & 3;             // ub 0..31, jp 0..3
    const int b_glob = bh * 32 + ub;
    const int jg = j_base + jp;
    float c_reg = 0.f, h_reg = 0.f, po_reg = 0.f;
    float bias_r[4];
    if (tid < 128) {
        c_reg = init_c[b_glob * HH + jg];
        h_reg = init_h[b_glob * HH + jg];
        #pragma unroll
        for (int gt = 0; gt < 4; ++gt) bias_r[gt] = bias[gt * 512 + jg];
    }
    for (int i = tid; i < 64 * 16; i += NTHR) m_lds[i] = mpack[i];

    const size_t OUT_HF = (size_t)BB * TT * HH;
    const size_t OUT_CF = OUT_HF + (size_t)BB * HH;
    const int arow = bt * 16 + (l & 15);
    const int rsw  = (arow & 7) << 4;

    // ---- prologue: stage x[0] (all threads) ----
    for (int u = tid; u < 2048; u += NTHR) {
        int row = u >> 6, c = u & 63;
        const float4* xp = (const float4*)(
            x + ((size_t)(bh * 32 + row) * TT + 0) * DD + 8 * c);
        float4 f0 = xp[0], f1 = xp[1];
        short8 v;
        v[0] = (short)f2bf(f0.x); v[1] = (short)f2bf(f0.y);
        v[2] = (short)f2bf(f0.z); v[3] = (short)f2bf(f0.w);
        v[4] = (short)f2bf(f1.x); v[5] = (short)f2bf(f1.y);
        v[6] = (short)f2bf(f1.z); v[7] = (short)f2bf(f1.w);
        *(short8*)(smem + row * 2048 + ((16 * c) ^ ((row & 7) << 4))) = v;
    }
    __syncthreads();

    for (int t = 0; t < TT; ++t) {
        // ---- x-MFMAs (A staged in previous tail) ----
        f32x4 acc = {0.f, 0.f, 0.f, 0.f};
        #pragma unroll
        for (int i = 0; i < 4; ++i) {
            int kt = ws * 4 + i;
            short8 a = *(const short8*)(
                smem + arow * 2048 + ((kt * 64 + (l >> 4) * 16) ^ rsw));
            acc = __builtin_amdgcn_mfma_f32_16x16x32_bf16(a, bf[i], acc, 0, 0, 0);
        }

        // ---- wait: the 128 same-half blocks reached step t ----
        if (w == 0) {
            const unsigned tgt = (unsigned)t;
            const unsigned* fb = flags + bh * 128;
            for (;;) {
                unsigned v0 = __hip_atomic_load(fb + l, __ATOMIC_RELAXED,
                                                __HIP_MEMORY_SCOPE_AGENT);
                unsigned v1 = __hip_atomic_load(fb + 64 + l, __ATOMIC_RELAXED,
                                                __HIP_MEMORY_SCOPE_AGENT);
                if (__all(v0 >= tgt && v1 >= tgt)) break;
                __builtin_amdgcn_s_sleep(2);
            }
        }
        __syncthreads();
        // acquire: invalidate stale L1/L2 lines so cached h loads are safe;
        // co-XCD blocks then share h through their L2 (vs per-block LLC trips)
        __builtin_amdgcn_fence(__ATOMIC_ACQUIRE, "agent");

        // ---- stage h -> LDS (cached dwordx4 loads) ----
        const uint4* curb4 = (const uint4*)(hbuf + (size_t)(t & 1) * (BB * HH / 2));
        #pragma unroll
        for (int i = 0; i < 4; ++i) {
            int row = 4 * w + i;
            uint4 hu = curb4[(size_t)(bh * 32 + row) * 64 + l];
            union { uint4 u; short8 v; } cv; cv.u = hu;
            *(short8*)(smem + row * 2048 +
                       ((1024 + 16 * l) ^ ((row & 7) << 4))) = cv.v;
        }
        __syncthreads();

        // ---- h-MFMAs + transposed zl write (17-pad: ~2-way banks) ----
        #pragma unroll
        for (int i = 0; i < 4; ++i) {
            int kt = 16 + ws * 4 + i;
            short8 a = *(const short8*)(
                smem + arow * 2048 + ((kt * 64 + (l >> 4) * 16) ^ rsw));
            acc = __builtin_amdgcn_mfma_f32_16x16x32_bf16(a, bf[4 + i], acc, 0, 0, 0);
        }
        #pragma unroll
        for (int r = 0; r < 4; ++r)
            zlp[((ws * 2 + bt) * 16 + (l & 15)) * 17 + (l >> 4) * 4 + r] = acc[r];
        __syncthreads();

        // ---- tail: update (waves 0-1) || stage x[t+1] (waves 2-7) ----
        unsigned* nxtb = hbuf + (size_t)((t + 1) & 1) * (BB * HH / 2);
        if (tid < 128) {
            const int bt_u = ub >> 4, m_u = ub & 15;
            bool msk = ((m_lds[b_glob * 16 + (t >> 5)] >> (t & 31)) & 1u) != 0u;
            float z[4];
            #pragma unroll
            for (int gt = 0; gt < 4; ++gt) {
                float s = bias_r[gt];
                #pragma unroll
                for (int p = 0; p < 4; ++p)
                    s += zlp[((p * 2 + bt_u) * 16 + gt * 4 + jp) * 17 + m_u];
                z[gt] = s;
            }
            float ig = fsig(z[0]);
            float fg = fsig(z[1]);
            float gg = ftanh_(z[2]);
            float og = fsig(z[3]);
            float c_new = fg * c_reg + ig * gg;
            float h_new = og * ftanh_(c_new);
            float ov = msk ? h_new : po_reg;
            float h2 = msk ? h_new : h_reg;
            float c2 = msk ? c_new : c_reg;
            out[((size_t)b_glob * TT + t) * HH + jg] = ov;
            unsigned hb = f2bf(h2);
            unsigned other = (unsigned)__shfl_xor((int)hb, 1);
            if ((jp & 1) == 0)
                __hip_atomic_store(nxtb + (size_t)b_glob * 256 + qid * 2 + (jp >> 1),
                                   hb | (other << 16), __ATOMIC_RELAXED,
                                   __HIP_MEMORY_SCOPE_AGENT);
            c_reg = c2; h_reg = h2; po_reg = ov;
        } else if (t + 1 < TT) {
            for (int u = tid - 128; u < 2048; u += 384) {
                int row = u >> 6, c = u & 63;
                const float4* xp = (const float4*)(
                    x + ((size_t)(bh * 32 + row) * TT + (t + 1)) * DD + 8 * c);
                float4 f0 = xp[0], f1 = xp[1];
                short8 v;
                v[0] = (short)f2bf(f0.x); v[1] = (short)f2bf(f0.y);
                v[2] = (short)f2bf(f0.z); v[3] = (short)f2bf(f0.w);
                v[4] = (short)f2bf(f1.x); v[5] = (short)f2bf(f1.y);
                v[6] = (short)f2bf(f1.z); v[7] = (short)f2bf(f1.w);
                *(short8*)(smem + row * 2048 + ((16 * c) ^ ((row & 7) << 4))) = v;
            }
        }
        // drains vmcnt per wave -> h sc1-stores at coherence point before flag
        __syncthreads();

        if (tid == 0)
            __hip_atomic_store(flags + bh * 128 + qid, (unsigned)(t + 1),
                               __ATOMIC_RELAXED, __HIP_MEMORY_SCOPE_AGENT);
    }

    if (tid < 128) {
        out[OUT_HF + (size_t)b_glob * HH + jg] = h_reg;
        out[OUT_CF + (size_t)b_glob * HH + jg] = c_reg;
    }
}

extern "C" void kernel_launch(void* const* d_in, const int* in_sizes, int n_in,
                              void* d_out, int out_size, void* d_ws, size_t ws_size,
                              hipStream_t stream) {
    const float* x      = (const float*)d_in[0];
    const float* init_h = (const float*)d_in[1];
    const float* init_c = (const float*)d_in[2];
    const float* Wx     = (const float*)d_in[3];
    const float* Wr     = (const float*)d_in[4];
    const float* bias   = (const float*)d_in[5];
    const int*   mask   = (const int*)d_in[6];
    float* out = (float*)d_out;

    unsigned short* WB    = (unsigned short*)d_ws;             // 4 MB
    unsigned*       hbuf  = (unsigned*)(WB + (size_t)GG * KK); // 128 KB
    unsigned*       flags = hbuf + 2 * (BB * HH / 2);          // 1 KB
    unsigned*       mpack = flags + NBLK;                      // 4 KB

    prep_kernel<<<(GG * KK + 255) / 256, 256, 0, stream>>>(
        Wx, Wr, init_h, mask, WB, hbuf, flags, mpack);

    void* args[] = { (void*)&x, (void*)&WB, (void*)&bias, (void*)&hbuf,
                     (void*)&flags, (void*)&mpack, (void*)&init_h,
                     (void*)&init_c, (void*)&out };
    (void)hipLaunchCooperativeKernel((const void*)lstm_kernel, dim3(NBLK),
                                     dim3(NTHR), args, (unsigned)LDS_BYTES,
                                     stream);
}

// Round 8
// 2882.747 us; speedup vs baseline: 3.1449x; 3.1449x over previous
//
#include <hip/hip_runtime.h>

constexpr int BB = 64, TT = 512, DD = 512, HH = 512;
constexpr int GG = 4 * HH;          // 2048 gate cols
constexpr int KK = DD + HH;         // 1024 fused K
constexpr int NBLK = 256, NTHR = 512;
// LDS: A[32][2048B] swizzled (64KB) | zl[4][2][16][17] f32 (8.5KB) | mask (4KB)
constexpr int LDS_A  = 32 * 2048;
constexpr int LDS_ZL = 4 * 2 * 16 * 17 * 4;
constexpr int LDS_BYTES = LDS_A + LDS_ZL + 64 * 16 * 4;

using short8 = __attribute__((ext_vector_type(8))) short;
using f32x4  = __attribute__((ext_vector_type(4))) float;

__device__ __host__ __forceinline__ unsigned short f2bf(float f) {
    union { float f; unsigned u; } v; v.f = f;
    unsigned u = v.u + 0x7fffu + ((v.u >> 16) & 1u);   // RNE
    return (unsigned short)(u >> 16);
}

__device__ __forceinline__ float fsig(float x) {       // inf-safe fast sigmoid
    return 1.f / (1.f + __expf(-x));
}
__device__ __forceinline__ float ftanh_(float x) {     // inf-safe fast tanh
    float e = __expf(2.f * fabsf(x));
    float r = 1.f - 2.f / (e + 1.f);
    return copysignf(r, x);
}

// ws: WB[2048][1024] bf16 (4MB) | hbuf[2][BB*HH/2] u32 pairs (128KB)
//     | flags[256] (1KB) | mpack[64][16] (4KB)

__global__ void prep_kernel(const float* __restrict__ Wx,   // [DD][GG]
                            const float* __restrict__ Wr,   // [HH][GG]
                            const float* __restrict__ init_h,
                            const int*   __restrict__ mask, // [B,T]
                            unsigned short* __restrict__ WB,
                            unsigned* __restrict__ hbuf0,
                            unsigned* __restrict__ flags,
                            unsigned* __restrict__ mpack) {
    int idx = blockIdx.x * blockDim.x + threadIdx.x;
    if (idx < GG * KK) {                 // WB[g][k] = W[k][g], bf16
        int g = idx >> 10, k = idx & 1023;
        float v = (k < DD) ? Wx[(size_t)k * GG + g]
                           : Wr[(size_t)(k - DD) * GG + g];
        WB[idx] = f2bf(v);
    }
    if (idx < BB * HH / 2) {             // h0 as packed bf16 pairs
        unsigned lo = f2bf(init_h[2 * idx]);
        unsigned hi = f2bf(init_h[2 * idx + 1]);
        hbuf0[idx] = lo | (hi << 16);
    }
    if (idx < NBLK) flags[idx] = 0u;
    if (idx < 64 * 16) {
        int b = idx >> 4, w = idx & 15;
        unsigned word = 0u;
        for (int tb = 0; tb < 32; ++tb)
            word |= (mask[b * TT + w * 32 + tb] != 0 ? 1u : 0u) << tb;
        mpack[idx] = word;
    }
}

__global__ void __launch_bounds__(NTHR, 1)
lstm_kernel(const float* __restrict__ x,          // [B,T,D]
            const unsigned short* __restrict__ WB,// [2048][1024] bf16
            const float* __restrict__ bias,       // [GG]
            unsigned*    hbuf,                    // [2][B*H/2] u32, sc1-only
            unsigned*    flags,                   // [256]: [bh*128 + qid]
            const unsigned* __restrict__ mpack,   // [64][16]
            const float* __restrict__ init_h,
            const float* __restrict__ init_c,
            float* __restrict__ out)              // outputs | h_f | c_f
{
    extern __shared__ char smem[];                // A: [32 rows][2048B] swizzled
    float*    zlp   = (float*)(smem + LDS_A);     // [4][2][16][17]
    unsigned* m_lds = (unsigned*)(smem + LDS_A + LDS_ZL);

    const int tid = threadIdx.x;
    const int bid = blockIdx.x;
    const int w   = tid >> 6;          // wave 0..7
    const int l   = tid & 63;
    const int bt  = w & 1;             // b-tile (16 rows)
    const int ws  = w >> 1;            // k-quarter 0..3
    const int bh     = (bid >> 3) & 1;                 // batch half
    const int qid    = (bid & 7) * 16 + (bid >> 4);    // j-quad 0..127
    const int j_base = qid * 4;

    // ---- persistent B-fragments (validated R6 layout) ----
    const int n = l & 15;
    const int g = (n >> 2) * 512 + j_base + (n & 3);
    short8 bf[8];
    {
        const unsigned short* wrow = WB + (size_t)g * KK + (l >> 4) * 8;
        #pragma unroll
        for (int i = 0; i < 8; ++i) {
            int kt = (i < 4) ? (ws * 4 + i) : (16 + ws * 4 + (i - 4));
            bf[i] = *(const short8*)(wrow + kt * 32);
        }
    }

    // ---- update mapping (tid < 128): one (b row, j col) each ----
    const int ub = tid >> 2, jp = tid & 3;             // ub 0..31, jp 0..3
    const int b_glob = bh * 32 + ub;
    const int jg = j_base + jp;
    float c_reg = 0.f, h_reg = 0.f, po_reg = 0.f;
    float bias_r[4];
    if (tid < 128) {
        c_reg = init_c[b_glob * HH + jg];
        h_reg = init_h[b_glob * HH + jg];
        #pragma unroll
        for (int gt = 0; gt < 4; ++gt) bias_r[gt] = bias[gt * 512 + jg];
    }
    for (int i = tid; i < 64 * 16; i += NTHR) m_lds[i] = mpack[i];

    const size_t OUT_HF = (size_t)BB * TT * HH;
    const size_t OUT_CF = OUT_HF + (size_t)BB * HH;
    const int arow = bt * 16 + (l & 15);
    const int rsw  = (arow & 7) << 4;

    // ---- prologue: stage x[0] (all threads) ----
    for (int u = tid; u < 2048; u += NTHR) {
        int row = u >> 6, c = u & 63;
        const float4* xp = (const float4*)(
            x + ((size_t)(bh * 32 + row) * TT + 0) * DD + 8 * c);
        float4 f0 = xp[0], f1 = xp[1];
        short8 v;
        v[0] = (short)f2bf(f0.x); v[1] = (short)f2bf(f0.y);
        v[2] = (short)f2bf(f0.z); v[3] = (short)f2bf(f0.w);
        v[4] = (short)f2bf(f1.x); v[5] = (short)f2bf(f1.y);
        v[6] = (short)f2bf(f1.z); v[7] = (short)f2bf(f1.w);
        *(short8*)(smem + row * 2048 + ((16 * c) ^ ((row & 7) << 4))) = v;
    }
    __syncthreads();

    for (int t = 0; t < TT; ++t) {
        // ---- (1) poll: ALL waves spin until same-half producers reach t ----
        {
            const unsigned tgt = (unsigned)t;
            const unsigned* fb = flags + bh * 128;
            for (;;) {
                unsigned v0 = __hip_atomic_load(fb + l, __ATOMIC_RELAXED,
                                                __HIP_MEMORY_SCOPE_AGENT);
                unsigned v1 = __hip_atomic_load(fb + 64 + l, __ATOMIC_RELAXED,
                                                __HIP_MEMORY_SCOPE_AGENT);
                if (__all(v0 >= tgt && v1 >= tgt)) break;
                __builtin_amdgcn_s_sleep(2);
            }
        }

        // ---- (2) issue h loads early (sc1, LLC-coherent) ----
        const unsigned* curb = hbuf + (size_t)(t & 1) * (BB * HH / 2);
        unsigned hv[4][4];
        #pragma unroll
        for (int i = 0; i < 4; ++i) {
            const unsigned* hp = curb + (size_t)(bh * 32 + 4 * w + i) * 256 + 4 * l;
            #pragma unroll
            for (int q = 0; q < 4; ++q)
                hv[i][q] = __hip_atomic_load(hp + q, __ATOMIC_RELAXED,
                                             __HIP_MEMORY_SCOPE_AGENT);
        }

        // ---- (3) x-MFMAs overlap the h-load latency ----
        f32x4 acc = {0.f, 0.f, 0.f, 0.f};
        #pragma unroll
        for (int i = 0; i < 4; ++i) {
            int kt = ws * 4 + i;
            short8 a = *(const short8*)(
                smem + arow * 2048 + ((kt * 64 + (l >> 4) * 16) ^ rsw));
            acc = __builtin_amdgcn_mfma_f32_16x16x32_bf16(a, bf[i], acc, 0, 0, 0);
        }

        // ---- (4) h -> LDS (compiler inserts vmcnt wait before ds_write) ----
        #pragma unroll
        for (int i = 0; i < 4; ++i) {
            int row = 4 * w + i;
            union { unsigned u[4]; short8 v; } cv;
            cv.u[0] = hv[i][0]; cv.u[1] = hv[i][1];
            cv.u[2] = hv[i][2]; cv.u[3] = hv[i][3];
            *(short8*)(smem + row * 2048 +
                       ((1024 + 16 * l) ^ ((row & 7) << 4))) = cv.v;
        }
        __syncthreads();

        // ---- (6) h-MFMAs + transposed zl write ----
        #pragma unroll
        for (int i = 0; i < 4; ++i) {
            int kt = 16 + ws * 4 + i;
            short8 a = *(const short8*)(
                smem + arow * 2048 + ((kt * 64 + (l >> 4) * 16) ^ rsw));
            acc = __builtin_amdgcn_mfma_f32_16x16x32_bf16(a, bf[4 + i], acc, 0, 0, 0);
        }
        #pragma unroll
        for (int r = 0; r < 4; ++r)
            zlp[((ws * 2 + bt) * 16 + (l & 15)) * 17 + (l >> 4) * 4 + r] = acc[r];
        __syncthreads();

        // ---- (8) update (waves 0-1) || stage x[t+1] (waves 2-7) ----
        unsigned* nxtb = hbuf + (size_t)((t + 1) & 1) * (BB * HH / 2);
        if (tid < 128) {
            const int bt_u = ub >> 4, m_u = ub & 15;
            bool msk = ((m_lds[b_glob * 16 + (t >> 5)] >> (t & 31)) & 1u) != 0u;
            float z[4];
            #pragma unroll
            for (int gt = 0; gt < 4; ++gt) {
                float s = bias_r[gt];
                #pragma unroll
                for (int p = 0; p < 4; ++p)
                    s += zlp[((p * 2 + bt_u) * 16 + gt * 4 + jp) * 17 + m_u];
                z[gt] = s;
            }
            float ig = fsig(z[0]);
            float fg = fsig(z[1]);
            float gg = ftanh_(z[2]);
            float og = fsig(z[3]);
            float c_new = fg * c_reg + ig * gg;
            float h_new = og * ftanh_(c_new);
            float ov = msk ? h_new : po_reg;
            float h2 = msk ? h_new : h_reg;
            float c2 = msk ? c_new : c_reg;
            out[((size_t)b_glob * TT + t) * HH + jg] = ov;
            unsigned hb = f2bf(h2);
            unsigned other = (unsigned)__shfl_xor((int)hb, 1);
            if ((jp & 1) == 0)
                __hip_atomic_store(nxtb + (size_t)b_glob * 256 + qid * 2 + (jp >> 1),
                                   hb | (other << 16), __ATOMIC_RELAXED,
                                   __HIP_MEMORY_SCOPE_AGENT);
            c_reg = c2; h_reg = h2; po_reg = ov;
        } else if (t + 1 < TT) {
            for (int u = tid - 128; u < 2048; u += 384) {
                int row = u >> 6, c = u & 63;
                const float4* xp = (const float4*)(
                    x + ((size_t)(bh * 32 + row) * TT + (t + 1)) * DD + 8 * c);
                float4 f0 = xp[0], f1 = xp[1];
                short8 v;
                v[0] = (short)f2bf(f0.x); v[1] = (short)f2bf(f0.y);
                v[2] = (short)f2bf(f0.z); v[3] = (short)f2bf(f0.w);
                v[4] = (short)f2bf(f1.x); v[5] = (short)f2bf(f1.y);
                v[6] = (short)f2bf(f1.z); v[7] = (short)f2bf(f1.w);
                *(short8*)(smem + row * 2048 + ((16 * c) ^ ((row & 7) << 4))) = v;
            }
        }
        // barrier drains vmcnt per wave -> h sc1-stores at coherence point
        // before the flag store below. No fences (sc1 both sides).
        __syncthreads();

        if (tid == 0)
            __hip_atomic_store(flags + bh * 128 + qid, (unsigned)(t + 1),
                               __ATOMIC_RELAXED, __HIP_MEMORY_SCOPE_AGENT);
    }

    if (tid < 128) {
        out[OUT_HF + (size_t)b_glob * HH + jg] = h_reg;
        out[OUT_CF + (size_t)b_glob * HH + jg] = c_reg;
    }
}

extern "C" void kernel_launch(void* const* d_in, const int* in_sizes, int n_in,
                              void* d_out, int out_size, void* d_ws, size_t ws_size,
                              hipStream_t stream) {
    const float* x      = (const float*)d_in[0];
    const float* init_h = (const float*)d_in[1];
    const float* init_c = (const float*)d_in[2];
    const float* Wx     = (const float*)d_in[3];
    const float* Wr     = (const float*)d_in[4];
    const float* bias   = (const float*)d_in[5];
    const int*   mask   = (const int*)d_in[6];
    float* out = (float*)d_out;

    unsigned short* WB    = (unsigned short*)d_ws;             // 4 MB
    unsigned*       hbuf  = (unsigned*)(WB + (size_t)GG * KK); // 128 KB
    unsigned*       flags = hbuf + 2 * (BB * HH / 2);          // 1 KB
    unsigned*       mpack = flags + NBLK;                      // 4 KB

    prep_kernel<<<(GG * KK + 255) / 256, 256, 0, stream>>>(
        Wx, Wr, init_h, mask, WB, hbuf, flags, mpack);

    void* args[] = { (void*)&x, (void*)&WB, (void*)&bias, (void*)&hbuf,
                     (void*)&flags, (void*)&mpack, (void*)&init_h,
                     (void*)&init_c, (void*)&out };
    (void)hipLaunchCooperativeKernel((const void*)lstm_kernel, dim3(NBLK),
                                     dim3(NTHR), args, (unsigned)LDS_BYTES,
                                     stream);
}

// Round 9
// 1848.299 us; speedup vs baseline: 4.9051x; 1.5597x over previous
//
#include <hip/hip_runtime.h>

constexpr int BB = 64, TT = 512, DD = 512, HH = 512;
constexpr int GG = 4 * HH;          // 2048 gate cols
constexpr int KK = DD + HH;         // 1024 fused K
constexpr int NBLK = 128, NTHR = 512;
// LDS: A[16 rows][2048B] swizzled (32KB) | zl[64][65] f32 (16.6KB) | mask 1KB
constexpr int LDS_A  = 16 * 2048;
constexpr int LDS_ZL = 64 * 65 * 4;
constexpr int LDS_BYTES = LDS_A + LDS_ZL + 16 * 16 * 4;

using short8 = __attribute__((ext_vector_type(8))) short;
using f32x4  = __attribute__((ext_vector_type(4))) float;

__device__ __host__ __forceinline__ unsigned short f2bf(float f) {
    union { float f; unsigned u; } v; v.f = f;
    unsigned u = v.u + 0x7fffu + ((v.u >> 16) & 1u);   // RNE
    return (unsigned short)(u >> 16);
}

__device__ __forceinline__ float fsig(float x) {
    return 1.f / (1.f + __expf(-x));
}
__device__ __forceinline__ float ftanh_(float x) {
    float e = __expf(2.f * fabsf(x));
    float r = 1.f - 2.f / (e + 1.f);
    return copysignf(r, x);
}

// ws: WB[2048][1024] bf16 (4MB) | hbuf[2][BB*HH/2] u32 pairs (128KB)
//     | flags[128] | mpack[64][16]

__global__ void prep_kernel(const float* __restrict__ Wx,   // [DD][GG]
                            const float* __restrict__ Wr,   // [HH][GG]
                            const float* __restrict__ init_h,
                            const int*   __restrict__ mask, // [B,T]
                            unsigned short* __restrict__ WB,
                            unsigned* __restrict__ hbuf0,
                            unsigned* __restrict__ flags,
                            unsigned* __restrict__ mpack) {
    int idx = blockIdx.x * blockDim.x + threadIdx.x;
    if (idx < GG * KK) {                 // WB[g][k] = W[k][g], bf16
        int g = idx >> 10, k = idx & 1023;
        float v = (k < DD) ? Wx[(size_t)k * GG + g]
                           : Wr[(size_t)(k - DD) * GG + g];
        WB[idx] = f2bf(v);
    }
    if (idx < BB * HH / 2) {             // h0 as packed bf16 pairs
        unsigned lo = f2bf(init_h[2 * idx]);
        unsigned hi = f2bf(init_h[2 * idx + 1]);
        hbuf0[idx] = lo | (hi << 16);
    }
    if (idx < NBLK) flags[idx] = 0u;
    if (idx < 64 * 16) {
        int b = idx >> 4, w = idx & 15;
        unsigned word = 0u;
        for (int tb = 0; tb < 32; ++tb)
            word |= (mask[b * TT + w * 32 + tb] != 0 ? 1u : 0u) << tb;
        mpack[idx] = word;
    }
}

__global__ void __launch_bounds__(NTHR, 1)
lstm_kernel(const float* __restrict__ x,          // [B,T,D]
            const unsigned short* __restrict__ WB,// [2048][1024] bf16
            const float* __restrict__ bias,       // [GG]
            unsigned*    hbuf,                    // [2][B*H/2] u32, sc1-only
            unsigned*    flags,                   // [128]: [qtr*32 + qb]
            const unsigned* __restrict__ mpack,   // [64][16]
            const float* __restrict__ init_h,
            const float* __restrict__ init_c,
            float* __restrict__ out)              // outputs | h_f | c_f
{
    extern __shared__ char smem[];                // A: [16 rows][2048B] swizzled
    float*    zlp   = (float*)(smem + LDS_A);     // [64][65]
    unsigned* m_lds = (unsigned*)(smem + LDS_A + LDS_ZL);  // [16][16]

    const int tid = threadIdx.x;
    const int bid = blockIdx.x;
    const int w   = tid >> 6;          // wave 0..7
    const int l   = tid & 63;
    const int kq  = w >> 1;            // k-quarter 0..3
    const int nh  = w & 1;             // n-half (n-tiles 2nh, 2nh+1)
    const int qtr = bid >> 5;          // batch quarter 0..3 (16 rows)
    const int qb  = bid & 31;          // j-slice in quarter
    const int j_base = qb * 16;

    // ---- persistent B-fragments: 8 ktiles x 2 n-tiles (64 VGPR) ----
    short8 bf[8][2];
    #pragma unroll
    for (int ni = 0; ni < 2; ++ni) {
        int col  = (2 * nh + ni) * 16 + (l & 15);
        int g    = (col >> 4) * 512 + j_base + (col & 15);
        const unsigned short* wrow = WB + (size_t)g * KK + (l >> 4) * 8;
        #pragma unroll
        for (int i = 0; i < 4; ++i) {
            bf[i][ni]     = *(const short8*)(wrow + (kq * 4 + i) * 32);
            bf[4 + i][ni] = *(const short8*)(wrow + (16 + kq * 4 + i) * 32);
        }
    }

    // ---- update mapping (tid < 256): one (row, j) each ----
    const int m_u = tid >> 4, jl = tid & 15;
    const int b_glob = qtr * 16 + m_u;
    const int jg = j_base + jl;
    float c_reg = 0.f, h_reg = 0.f, po_reg = 0.f;
    float bias_r[4];
    if (tid < 256) {
        c_reg = init_c[b_glob * HH + jg];
        h_reg = init_h[b_glob * HH + jg];
        #pragma unroll
        for (int gt = 0; gt < 4; ++gt) bias_r[gt] = bias[gt * 512 + jg];
    }
    for (int i = tid; i < 256; i += NTHR)
        m_lds[i] = mpack[(qtr * 16 + (i >> 4)) * 16 + (i & 15)];

    const size_t OUT_HF = (size_t)BB * TT * HH;
    const size_t OUT_CF = OUT_HF + (size_t)BB * HH;
    const int arow = l & 15;
    const int rsw  = (arow & 7) << 4;
    const int hrow = 2 * w + (l >> 5);             // h-stage row per lane
    const int hsw  = (hrow & 7) << 4;

    // ---- prologue: stage x[0] ----
    for (int u = tid; u < 1024; u += NTHR) {
        int row = u >> 6, c = u & 63;
        const float4* xp = (const float4*)(
            x + ((size_t)(qtr * 16 + row) * TT + 0) * DD + 8 * c);
        float4 f0 = xp[0], f1 = xp[1];
        short8 v;
        v[0] = (short)f2bf(f0.x); v[1] = (short)f2bf(f0.y);
        v[2] = (short)f2bf(f0.z); v[3] = (short)f2bf(f0.w);
        v[4] = (short)f2bf(f1.x); v[5] = (short)f2bf(f1.y);
        v[6] = (short)f2bf(f1.z); v[7] = (short)f2bf(f1.w);
        *(short8*)(smem + row * 2048 + ((16 * c) ^ ((row & 7) << 4))) = v;
    }
    __syncthreads();

    for (int t = 0; t < TT; ++t) {
        // ---- (1) poll own quarter's 32 flags (all waves, 1 flag/lane) ----
        {
            const unsigned tgt = (unsigned)t;
            const unsigned* fb = flags + qtr * 32;
            for (;;) {
                unsigned v = __hip_atomic_load(fb + (l & 31), __ATOMIC_RELAXED,
                                               __HIP_MEMORY_SCOPE_AGENT);
                if (__all(v >= tgt)) break;
                __builtin_amdgcn_s_sleep(1);
            }
        }

        // ---- (2) issue h loads: 2x dwordx4 sc1 per lane (coalesced) ----
        const unsigned* hp = hbuf + (size_t)(t & 1) * (BB * HH / 2)
                             + (size_t)(qtr * 16 + hrow) * 256 + (l & 31) * 8;
        uint4 ha, hb;
        asm volatile("global_load_dwordx4 %0, %2, off sc1\n\t"
                     "global_load_dwordx4 %1, %3, off sc1"
                     : "=&v"(ha), "=&v"(hb)
                     : "v"(hp), "v"(hp + 4) : "memory");

        // ---- (3) x-MFMAs overlap the h-load latency ----
        f32x4 acc0 = {0.f, 0.f, 0.f, 0.f}, acc1 = {0.f, 0.f, 0.f, 0.f};
        #pragma unroll
        for (int i = 0; i < 4; ++i) {
            int kt = kq * 4 + i;
            short8 a = *(const short8*)(
                smem + arow * 2048 + ((kt * 64 + (l >> 4) * 16) ^ rsw));
            acc0 = __builtin_amdgcn_mfma_f32_16x16x32_bf16(a, bf[i][0], acc0, 0, 0, 0);
            acc1 = __builtin_amdgcn_mfma_f32_16x16x32_bf16(a, bf[i][1], acc1, 0, 0, 0);
        }

        // ---- (4) wait loads, h -> LDS ----
        asm volatile("s_waitcnt vmcnt(0)" ::: "memory");
        __builtin_amdgcn_sched_barrier(0);
        {
            union { uint4 u; short8 v; } c0, c1;
            c0.u = ha; c1.u = hb;
            char* dst = smem + hrow * 2048;
            int off = 1024 + (l & 31) * 32;
            *(short8*)(dst + (off ^ hsw)) = c0.v;
            *(short8*)(dst + ((off + 16) ^ hsw)) = c1.v;
        }
        __syncthreads();

        // ---- (5) h-MFMAs + zl write (65-stride pad) ----
        #pragma unroll
        for (int i = 0; i < 4; ++i) {
            int kt = 16 + kq * 4 + i;
            short8 a = *(const short8*)(
                smem + arow * 2048 + ((kt * 64 + (l >> 4) * 16) ^ rsw));
            acc0 = __builtin_amdgcn_mfma_f32_16x16x32_bf16(a, bf[4 + i][0], acc0, 0, 0, 0);
            acc1 = __builtin_amdgcn_mfma_f32_16x16x32_bf16(a, bf[4 + i][1], acc1, 0, 0, 0);
        }
        #pragma unroll
        for (int r = 0; r < 4; ++r) {
            int zrow = kq * 16 + (l >> 4) * 4 + r;
            zlp[zrow * 65 + (2 * nh) * 16 + (l & 15)]     = acc0[r];
            zlp[zrow * 65 + (2 * nh + 1) * 16 + (l & 15)] = acc1[r];
        }
        __syncthreads();

        // ---- (6) update (waves 0-3) || stage x[t+1] (waves 4-7) ----
        unsigned* nxtb = hbuf + (size_t)((t + 1) & 1) * (BB * HH / 2);
        if (tid < 256) {
            bool msk = ((m_lds[m_u * 16 + (t >> 5)] >> (t & 31)) & 1u) != 0u;
            float z[4];
            #pragma unroll
            for (int gt = 0; gt < 4; ++gt) {
                float s = bias_r[gt];
                #pragma unroll
                for (int p = 0; p < 4; ++p)
                    s += zlp[(p * 16 + m_u) * 65 + gt * 16 + jl];
                z[gt] = s;
            }
            float ig = fsig(z[0]);
            float fg = fsig(z[1]);
            float gg = ftanh_(z[2]);
            float og = fsig(z[3]);
            float c_new = fg * c_reg + ig * gg;
            float h_new = og * ftanh_(c_new);
            float ov = msk ? h_new : po_reg;
            float h2 = msk ? h_new : h_reg;
            float c2 = msk ? c_new : c_reg;
            out[((size_t)b_glob * TT + t) * HH + jg] = ov;
            unsigned hb16 = f2bf(h2);
            unsigned other = (unsigned)__shfl_xor((int)hb16, 1);
            if ((jl & 1) == 0)
                __hip_atomic_store(nxtb + (size_t)b_glob * 256 + ((j_base + jl) >> 1),
                                   hb16 | (other << 16), __ATOMIC_RELAXED,
                                   __HIP_MEMORY_SCOPE_AGENT);
            c_reg = c2; h_reg = h2; po_reg = ov;
        } else if (t + 1 < TT) {
            for (int u = tid - 256; u < 1024; u += 256) {
                int row = u >> 6, c = u & 63;
                const float4* xp = (const float4*)(
                    x + ((size_t)(qtr * 16 + row) * TT + (t + 1)) * DD + 8 * c);
                float4 f0 = xp[0], f1 = xp[1];
                short8 v;
                v[0] = (short)f2bf(f0.x); v[1] = (short)f2bf(f0.y);
                v[2] = (short)f2bf(f0.z); v[3] = (short)f2bf(f0.w);
                v[4] = (short)f2bf(f1.x); v[5] = (short)f2bf(f1.y);
                v[6] = (short)f2bf(f1.z); v[7] = (short)f2bf(f1.w);
                *(short8*)(smem + row * 2048 + ((16 * c) ^ ((row & 7) << 4))) = v;
            }
        }
        // barrier drains vmcnt -> h sc1-stores at coherence point before flag
        __syncthreads();

        if (tid == 0)
            __hip_atomic_store(flags + qtr * 32 + qb, (unsigned)(t + 1),
                               __ATOMIC_RELAXED, __HIP_MEMORY_SCOPE_AGENT);
    }

    if (tid < 256) {
        out[OUT_HF + (size_t)b_glob * HH + jg] = h_reg;
        out[OUT_CF + (size_t)b_glob * HH + jg] = c_reg;
    }
}

extern "C" void kernel_launch(void* const* d_in, const int* in_sizes, int n_in,
                              void* d_out, int out_size, void* d_ws, size_t ws_size,
                              hipStream_t stream) {
    const float* x      = (const float*)d_in[0];
    const float* init_h = (const float*)d_in[1];
    const float* init_c = (const float*)d_in[2];
    const float* Wx     = (const float*)d_in[3];
    const float* Wr     = (const float*)d_in[4];
    const float* bias   = (const float*)d_in[5];
    const int*   mask   = (const int*)d_in[6];
    float* out = (float*)d_out;

    unsigned short* WB    = (unsigned short*)d_ws;             // 4 MB
    unsigned*       hbuf  = (unsigned*)(WB + (size_t)GG * KK); // 128 KB
    unsigned*       flags = hbuf + 2 * (BB * HH / 2);
    unsigned*       mpack = flags + NBLK;

    prep_kernel<<<(GG * KK + 255) / 256, 256, 0, stream>>>(
        Wx, Wr, init_h, mask, WB, hbuf, flags, mpack);

    void* args[] = { (void*)&x, (void*)&WB, (void*)&bias, (void*)&hbuf,
                     (void*)&flags, (void*)&mpack, (void*)&init_h,
                     (void*)&init_c, (void*)&out };
    (void)hipLaunchCooperativeKernel((const void*)lstm_kernel, dim3(NBLK),
                                     dim3(NTHR), args, (unsigned)LDS_BYTES,
                                     stream);
}